// Round 3
// baseline (200.551 us; speedup 1.0000x reference)
//
#include <hip/hip_runtime.h>

// Round 3: two barrier-free kernels through d_ws.
//   proj_qkv: x[B,T,64] -> Q(scaled),K row-major bf16 + V^T bf16 in workspace.
//             All outputs stored as packed bf16x4 via transposed-product
//             C-frag layouts; no LDS, no syncthreads.
//   attn:     one wave per 16-row q-strip; S^T = K.Q^T with native K=32 MFMA
//             (both operands are contiguous row-major global b128 loads);
//             P^T = exp(S^T) chains directly into O^T += V^T.P^T via K=16
//             MFMA emulated on 16x16x32 (zero-padded upper k). No LDS at all.
// MFMA layouts (guide-verified, m89/m91):
//   A: lane holds A[m=lane&15][k=(lane>>4)*8+j]
//   B: lane holds B[k=(lane>>4)*8+j][n=lane&15]
//   C/D: lane holds D[row=(lane>>4)*4+r][col=lane&15]

#define SEQ 512
#define CH  64

typedef __attribute__((ext_vector_type(8))) short bf16x8;
typedef __attribute__((ext_vector_type(4))) short bf16x4;
typedef __attribute__((ext_vector_type(4))) float f32x4;

static __device__ __forceinline__ short f2bf(float f) {
  union { float f; unsigned u; } v; v.f = f;
  unsigned r = v.u + 0x7FFFu + ((v.u >> 16) & 1u);   // RNE
  return (short)(r >> 16);
}

static __device__ __forceinline__ bf16x4 pack4(f32x4 v) {
  bf16x4 r;
  r[0] = f2bf(v[0]); r[1] = f2bf(v[1]); r[2] = f2bf(v[2]); r[3] = f2bf(v[3]);
  return r;
}

static __device__ __forceinline__ f32x4 mfma32(bf16x8 a, bf16x8 b, f32x4 c) {
  return __builtin_amdgcn_mfma_f32_16x16x32_bf16(a, b, c, 0, 0, 0);
}

// K=16 MFMA on the K=32 unit: logical k16=quad*4+j embeds at k32=quad*8+j on
// both operands (injective, consistent); padded k-slots are zero on both sides.
static __device__ __forceinline__ f32x4 mfma16(bf16x4 a, bf16x4 b, f32x4 c) {
  bf16x8 a8 = {a[0], a[1], a[2], a[3], (short)0, (short)0, (short)0, (short)0};
  bf16x8 b8 = {b[0], b[1], b[2], b[3], (short)0, (short)0, (short)0, (short)0};
  return __builtin_amdgcn_mfma_f32_16x16x32_bf16(a8, b8, c, 0, 0, 0);
}

// ---------------- kernel 1: QKV projection ----------------
// grid 1024: block -> (batch = blk>>2, quarter = blk&3); wave owns 32 tokens.
__global__ __launch_bounds__(256, 2)
void proj_qkv(const float* __restrict__ x,
              const float* __restrict__ wk,
              const float* __restrict__ wq,
              const float* __restrict__ wv,
              unsigned short* __restrict__ Qg,
              unsigned short* __restrict__ Kg,
              unsigned short* __restrict__ Vt) {
  const int blk  = blockIdx.x;
  const int b    = blk >> 2;
  const int qd   = blk & 3;
  const int w    = threadIdx.x >> 6;
  const int lane = threadIdx.x & 63;
  const int l15  = lane & 15;
  const int quad = lane >> 4;

  const float* xb = x + (size_t)b * SEQ * CH;
  unsigned short* Qb = Qg + (size_t)b * SEQ * CH;
  unsigned short* Kb = Kg + (size_t)b * SEQ * CH;
  unsigned short* Vb = Vt + (size_t)b * CH * SEQ;

  // Weight fragments. Same register content serves as:
  //   WQ/WK: A-operand of W^T.x^T  (A[m=ch=t*16+l15][k=cc=c*32+quad*8+j])
  //   WV:    B-operand of x.W      (B[k=cc][n=ch])
  // both read w[cc][ch].
  bf16x8 WQ[4][2], WK[4][2], WV[4][2];
#pragma unroll
  for (int t = 0; t < 4; ++t)
#pragma unroll
    for (int c = 0; c < 2; ++c) {
      const int k0 = c * 32 + quad * 8;
      const int n  = t * 16 + l15;
      bf16x8 fq, fk, fv;
#pragma unroll
      for (int j = 0; j < 8; ++j) {
        fq[j] = f2bf(wq[(k0 + j) * CH + n] * 0.125f);  // fold C^-0.5 into Q
        fk[j] = f2bf(wk[(k0 + j) * CH + n]);
        fv[j] = f2bf(wv[(k0 + j) * CH + n]);
      }
      WQ[t][c] = fq; WK[t][c] = fk; WV[t][c] = fv;
    }

#pragma unroll
  for (int sub = 0; sub < 2; ++sub) {
    const int t16 = qd * 128 + w * 32 + sub * 16;
    bf16x8 xa[2];
#pragma unroll
    for (int c = 0; c < 2; ++c) {
      const float* px = xb + (t16 + l15) * CH + c * 32 + quad * 8;
      float4 lo = *(const float4*)px;
      float4 hi = *(const float4*)(px + 4);
      bf16x8 f;
      f[0] = f2bf(lo.x); f[1] = f2bf(lo.y); f[2] = f2bf(lo.z); f[3] = f2bf(lo.w);
      f[4] = f2bf(hi.x); f[5] = f2bf(hi.y); f[6] = f2bf(hi.z); f[7] = f2bf(hi.w);
      xa[c] = f;
    }
    // Q^T, K^T C-frags -> packed row-major stores Q[t][4ch], K[t][4ch]
#pragma unroll
    for (int cht = 0; cht < 4; ++cht) {
      f32x4 aq = {0.f,0.f,0.f,0.f}, ak = {0.f,0.f,0.f,0.f};
#pragma unroll
      for (int c = 0; c < 2; ++c) {
        aq = mfma32(WQ[cht][c], xa[c], aq);   // Q^T[ch=cht*16+quad*4+r][t16+l15]
        ak = mfma32(WK[cht][c], xa[c], ak);
      }
      const size_t e = (size_t)(t16 + l15) * CH + cht * 16 + quad * 4;
      *(bf16x4*)(Qb + e) = pack4(aq);
      *(bf16x4*)(Kb + e) = pack4(ak);
    }
    // V row-major C-frags -> packed V^T stores Vt[ch][4t]
#pragma unroll
    for (int nt = 0; nt < 4; ++nt) {
      f32x4 av = {0.f,0.f,0.f,0.f};
#pragma unroll
      for (int c = 0; c < 2; ++c)
        av = mfma32(xa[c], WV[nt][c], av);    // V[t16+quad*4+r][nt*16+l15]
      *(bf16x4*)(Vb + (size_t)(nt * 16 + l15) * SEQ + t16 + quad * 4) = pack4(av);
    }
  }
}

// ---------------- kernel 2: flash attention, one wave per strip ----------------
// grid 2048: b = blk & 255 (keeps same-batch blocks on one XCD via blk%8),
// jg = 7 - (blk>>8) (longest strips dispatched first). Wave w -> strip 4*jg+w.
__global__ __launch_bounds__(256, 4)
void attn(const unsigned short* __restrict__ Qg,
          const unsigned short* __restrict__ Kg,
          const unsigned short* __restrict__ Vt,
          float* __restrict__ out) {
  const int blk  = blockIdx.x;
  const int b    = blk & 255;
  const int jg   = 7 - (blk >> 8);
  const int w    = threadIdx.x >> 6;
  const int lane = threadIdx.x & 63;
  const int l15  = lane & 15;
  const int quad = lane >> 4;

  const int s  = jg * 4 + w;     // strip 0..31
  const int q0 = s * 16;

  const unsigned short* Qb = Qg + (size_t)b * SEQ * CH;
  const unsigned short* Kb = Kg + (size_t)b * SEQ * CH;
  const unsigned short* Vb = Vt + (size_t)b * CH * SEQ;
  float* outb = out + (size_t)b * SEQ * CH;

  // Q B-frags for S^T = K . Q^T (k=ch): contiguous row-major b128 loads
  bf16x8 qf[2];
#pragma unroll
  for (int c = 0; c < 2; ++c)
    qf[c] = *(const bf16x8*)(Qb + (size_t)(q0 + l15) * CH + c * 32 + quad * 8);

  f32x4 ot[4];
#pragma unroll
  for (int cht = 0; cht < 4; ++cht) ot[cht] = (f32x4){0.f,0.f,0.f,0.f};
  float ls = 0.f;

#pragma unroll 1
  for (int kt = 0; kt <= s; ++kt) {
    const int kb = kt * 16;
    // S^T subtile: lane holds S^T[kb+quad*4+r][q0+l15]
    bf16x8 kf0 = *(const bf16x8*)(Kb + (size_t)(kb + l15) * CH + quad * 8);
    bf16x8 kf1 = *(const bf16x8*)(Kb + (size_t)(kb + l15) * CH + 32 + quad * 8);
    f32x4 st = {0.f,0.f,0.f,0.f};
    st = mfma32(kf0, qf[0], st);
    st = mfma32(kf1, qf[1], st);
    if (kt == s) {   // diagonal mask: key kb+quad*4+r > query q0+l15 (kb==q0)
#pragma unroll
      for (int r = 0; r < 4; ++r)
        if (quad * 4 + r > l15) st[r] = -1e30f;
    }
#pragma unroll
    for (int r = 0; r < 4; ++r) {
      const float e = __expf(st[r]);
      ls += e;
      st[r] = e;
    }
    const bf16x4 pp = pack4(st);   // P^T B-operand (k=key=quad*4+j) for K=16
    // O^T[ch][q] += V^T[ch][key] . P^T[key][q]
#pragma unroll
    for (int cht = 0; cht < 4; ++cht) {
      bf16x4 vf = *(const bf16x4*)(Vb + (size_t)(cht * 16 + l15) * SEQ + kb + quad * 4);
      ot[cht] = mfma16(vf, pp, ot[cht]);
    }
  }

  // per-lane partials cover keys {quad*4+r}: sum across the 4 quads
  ls += __shfl_xor(ls, 16);
  ls += __shfl_xor(ls, 32);
  const float inv = 1.0f / ls;

#pragma unroll
  for (int cht = 0; cht < 4; ++cht) {
    float4 v;
    v.x = ot[cht][0] * inv; v.y = ot[cht][1] * inv;
    v.z = ot[cht][2] * inv; v.w = ot[cht][3] * inv;
    *(float4*)(outb + (size_t)(q0 + l15) * CH + cht * 16 + quad * 4) = v;
  }
}

extern "C" void kernel_launch(void* const* d_in, const int* in_sizes, int n_in,
                              void* d_out, int out_size, void* d_ws, size_t ws_size,
                              hipStream_t stream) {
  const float* x  = (const float*)d_in[0];
  const float* wk = (const float*)d_in[1];   // w_key
  const float* wq = (const float*)d_in[2];   // w_query
  const float* wv = (const float*)d_in[3];   // w_value
  (void)in_sizes; (void)n_in; (void)out_size; (void)ws_size;

  const size_t mat = (size_t)256 * SEQ * CH;           // elements per bf16 matrix
  unsigned short* Qg = (unsigned short*)d_ws;          // needs 3*mat*2 = 50.3 MB
  unsigned short* Kg = Qg + mat;
  unsigned short* Vt = Kg + mat;

  proj_qkv<<<1024, 256, 0, stream>>>(x, wk, wq, wv, Qg, Kg, Vt);
  attn<<<2048, 256, 0, stream>>>(Qg, Kg, Vt, (float*)d_out);
}

// Round 4
// 124.550 us; speedup vs baseline: 1.6102x; 1.6102x over previous
//
#include <hip/hip_runtime.h>

// Round 4: fragment-native workspace layouts -> all attn loads perfectly
// coalesced (base + lane*16B); all MFMAs native K=32.
//
// Layouts (per batch, shorts):
//  Qws/Kws: per 16-token block i, chunk c (ch half), lane=q*16+l15, j=0..7:
//    idx = i*1024 + c*512 + lane*8 + j   holds  M[16i+l15][32c+8q+j]
//    (exactly the A/B fragment image for the S^T=K.Q^T MFMA)
//  Vws: per 32-key group g, ch-tile cht, lane=q*16+l15, j:
//    idx = g*2048 + cht*512 + lane*8 + j holds V[32g + keyperm(q,j)][16cht+l15]
//    keyperm(q,j) = 4q + (j&3) + 16*(j>>2)  -- chosen so the PV B-operand is
//    the raw concatenation of the two packed S^T C-frags (zero data movement).
// MFMA layouts (guide-verified): A[m=l15][k=q*8+j], B[k=q*8+j][n=l15],
// C/D[row=4q+r][col=l15].

#define SEQ 512
#define CH  64

typedef __attribute__((ext_vector_type(8))) short bf16x8;
typedef __attribute__((ext_vector_type(4))) short bf16x4;
typedef __attribute__((ext_vector_type(4))) float f32x4;

static __device__ __forceinline__ short f2bf(float f) {
  union { float f; unsigned u; } v; v.f = f;
  unsigned r = v.u + 0x7FFFu + ((v.u >> 16) & 1u);   // RNE
  return (short)(r >> 16);
}

static __device__ __forceinline__ bf16x4 pack4(f32x4 v) {
  bf16x4 r;
  r[0] = f2bf(v[0]); r[1] = f2bf(v[1]); r[2] = f2bf(v[2]); r[3] = f2bf(v[3]);
  return r;
}

static __device__ __forceinline__ bf16x8 cat44(bf16x4 a, bf16x4 b) {
  bf16x8 r;
  r[0] = a[0]; r[1] = a[1]; r[2] = a[2]; r[3] = a[3];
  r[4] = b[0]; r[5] = b[1]; r[6] = b[2]; r[7] = b[3];
  return r;
}

static __device__ __forceinline__ f32x4 mfma32(bf16x8 a, bf16x8 b, f32x4 c) {
  return __builtin_amdgcn_mfma_f32_16x16x32_bf16(a, b, c, 0, 0, 0);
}

// ---------------- kernel 1: QKV projection into fragment-native ws ----------------
__global__ __launch_bounds__(256, 2)
void proj_qkv(const float* __restrict__ x,
              const float* __restrict__ wk,
              const float* __restrict__ wq,
              const float* __restrict__ wv,
              unsigned short* __restrict__ Qw,
              unsigned short* __restrict__ Kw,
              unsigned short* __restrict__ Vw) {
  const int blk  = blockIdx.x;
  const int b    = blk >> 2;
  const int qd   = blk & 3;
  const int w    = threadIdx.x >> 6;
  const int lane = threadIdx.x & 63;
  const int l15  = lane & 15;
  const int quad = lane >> 4;

  const float* xb = x + (size_t)b * SEQ * CH;
  unsigned short* Qb = Qw + (size_t)b * SEQ * CH;
  unsigned short* Kb = Kw + (size_t)b * SEQ * CH;
  unsigned short* Vb = Vw + (size_t)b * SEQ * CH;

  // WQ/WK as A-operand of W^T.x^T ; WV as B-operand of x.W (same read pattern)
  bf16x8 WQ[4][2], WK[4][2], WV[4][2];
#pragma unroll
  for (int t = 0; t < 4; ++t)
#pragma unroll
    for (int c = 0; c < 2; ++c) {
      const int k0 = c * 32 + quad * 8;
      const int n  = t * 16 + l15;
      bf16x8 fq, fk, fv;
#pragma unroll
      for (int j = 0; j < 8; ++j) {
        fq[j] = f2bf(wq[(k0 + j) * CH + n] * 0.125f);  // fold C^-0.5 into Q
        fk[j] = f2bf(wk[(k0 + j) * CH + n]);
        fv[j] = f2bf(wv[(k0 + j) * CH + n]);
      }
      WQ[t][c] = fq; WK[t][c] = fk; WV[t][c] = fv;
    }

#pragma unroll
  for (int sub = 0; sub < 2; ++sub) {
    const int t16 = qd * 128 + w * 32 + sub * 16;
    bf16x8 xa[2];
#pragma unroll
    for (int c = 0; c < 2; ++c) {
      const float* px = xb + (size_t)(t16 + l15) * CH + c * 32 + quad * 8;
      float4 lo = *(const float4*)px;
      float4 hi = *(const float4*)(px + 4);
      bf16x8 f;
      f[0] = f2bf(lo.x); f[1] = f2bf(lo.y); f[2] = f2bf(lo.z); f[3] = f2bf(lo.w);
      f[4] = f2bf(hi.x); f[5] = f2bf(hi.y); f[6] = f2bf(hi.z); f[7] = f2bf(hi.w);
      xa[c] = f;
    }
    // Q^T/K^T C-frags (lane: ch=16cht+4q+r, t=t16+l15) -> frag-image stores
#pragma unroll
    for (int cht = 0; cht < 4; ++cht) {
      f32x4 aq = {0.f,0.f,0.f,0.f}, ak = {0.f,0.f,0.f,0.f};
#pragma unroll
      for (int c = 0; c < 2; ++c) {
        aq = mfma32(WQ[cht][c], xa[c], aq);
        ak = mfma32(WK[cht][c], xa[c], ak);
      }
      const int cdst = cht >> 1;
      const int qp   = ((cht & 1) << 1) | (quad >> 1);
      const size_t off = (size_t)(t16 >> 4) * 1024 + cdst * 512 +
                         (qp * 16 + l15) * 8 + (quad & 1) * 4;
      *(bf16x4*)(Qb + off) = pack4(aq);
      *(bf16x4*)(Kb + off) = pack4(ak);
    }
    // V C-frags (lane: t=t16+4q+r, ch=16nt+l15) -> key-permuted V^T frag image
    const int g = t16 >> 5, sh = (t16 >> 4) & 1;
#pragma unroll
    for (int nt = 0; nt < 4; ++nt) {
      f32x4 av = {0.f,0.f,0.f,0.f};
#pragma unroll
      for (int c = 0; c < 2; ++c)
        av = mfma32(xa[c], WV[nt][c], av);
      const size_t voff = (size_t)g * 2048 + nt * 512 +
                          (quad * 16 + l15) * 8 + sh * 4;
      *(bf16x4*)(Vb + voff) = pack4(av);
    }
  }
}

// ---------------- kernel 2: flash attention, q-tile 32 per wave ----------------
// grid 1024: b = blk & 255, sg = blk >> 8 (0..3).
// wave w -> strip s in {sg, 7-sg, 8+sg, 15-sg}: 34 key-groups per block.
__global__ __launch_bounds__(256, 4)
void attn(const unsigned short* __restrict__ Qw,
          const unsigned short* __restrict__ Kw,
          const unsigned short* __restrict__ Vw,
          float* __restrict__ out) {
  const int blk  = blockIdx.x;
  const int b    = blk & 255;
  const int sg   = blk >> 8;
  const int w    = threadIdx.x >> 6;
  const int lane = threadIdx.x & 63;
  const int l15  = lane & 15;
  const int quad = lane >> 4;

  const int s  = ((w & 2) ? 8 : 0) + ((w & 1) ? 7 - sg : sg);  // strip 0..15
  const int q0 = s * 32;

  const unsigned short* Qb = Qw + (size_t)b * SEQ * CH;
  const unsigned short* Kb = Kw + (size_t)b * SEQ * CH;
  const unsigned short* Vb = Vw + (size_t)b * SEQ * CH;
  float* outb = out + (size_t)b * SEQ * CH;

  // Q B-frags for the two 16-col subtiles (nn) -- coalesced b128 loads
  bf16x8 qf[2][2];
#pragma unroll
  for (int nn = 0; nn < 2; ++nn)
#pragma unroll
    for (int c = 0; c < 2; ++c)
      qf[nn][c] = *(const bf16x8*)(Qb + (size_t)(2 * s + nn) * 1024 + c * 512 + lane * 8);

  f32x4 ot[2][4];
#pragma unroll
  for (int nn = 0; nn < 2; ++nn)
#pragma unroll
    for (int cht = 0; cht < 4; ++cht) ot[nn][cht] = (f32x4){0.f,0.f,0.f,0.f};
  float ls0 = 0.f, ls1 = 0.f;

  const int dthr = l15 - quad * 4;   // diag mask: r > dthr

#pragma unroll 1
  for (int kt = 0; kt <= s; ++kt) {
    const bool diag = (kt == s);
    const unsigned short* kp = Kb + (size_t)kt * 2048;
    bf16x8 kf00 = *(const bf16x8*)(kp + lane * 8);          // keys 0-15, ch 0-31
    bf16x8 kf01 = *(const bf16x8*)(kp + 512  + lane * 8);   // keys 0-15, ch 32-63
    bf16x8 kf10 = *(const bf16x8*)(kp + 1024 + lane * 8);   // keys 16-31, ch 0-31
    bf16x8 kf11 = *(const bf16x8*)(kp + 1536 + lane * 8);   // keys 16-31, ch 32-63

    // S^T subtiles: st[mm][nn], rows=keys 32kt+16mm+4q+r, cols=q0+16nn+l15
    f32x4 st00 = {0.f,0.f,0.f,0.f}, st01 = {0.f,0.f,0.f,0.f};
    f32x4 st10 = {0.f,0.f,0.f,0.f}, st11 = {0.f,0.f,0.f,0.f};
    st00 = mfma32(kf00, qf[0][0], st00); st00 = mfma32(kf01, qf[0][1], st00);
    st01 = mfma32(kf00, qf[1][0], st01); st01 = mfma32(kf01, qf[1][1], st01);
    st11 = mfma32(kf10, qf[1][0], st11); st11 = mfma32(kf11, qf[1][1], st11);
    if (!diag) {
      st10 = mfma32(kf10, qf[0][0], st10); st10 = mfma32(kf11, qf[0][1], st10);
    }

    const unsigned short* vp = Vb + (size_t)kt * 2048;
    bf16x8 vf0 = *(const bf16x8*)(vp + lane * 8);
    bf16x8 vf1 = *(const bf16x8*)(vp + 512  + lane * 8);
    bf16x8 vf2 = *(const bf16x8*)(vp + 1024 + lane * 8);
    bf16x8 vf3 = *(const bf16x8*)(vp + 1536 + lane * 8);

    bf16x8 pp0, pp1;
    if (diag) {
#pragma unroll
      for (int r = 0; r < 4; ++r) {
        st00[r] = (r > dthr) ? 0.f : __expf(st00[r]);  ls0 += st00[r];
        st11[r] = (r > dthr) ? 0.f : __expf(st11[r]);  ls1 += st11[r];
        st01[r] = __expf(st01[r]);                     ls1 += st01[r];
      }
      pp0 = cat44(pack4(st00), (bf16x4){0,0,0,0});   // keys 16-31 masked for cols 0-15
      pp1 = cat44(pack4(st01), pack4(st11));
    } else {
#pragma unroll
      for (int r = 0; r < 4; ++r) {
        st00[r] = __expf(st00[r]);  ls0 += st00[r];
        st10[r] = __expf(st10[r]);  ls0 += st10[r];
        st01[r] = __expf(st01[r]);  ls1 += st01[r];
        st11[r] = __expf(st11[r]);  ls1 += st11[r];
      }
      pp0 = cat44(pack4(st00), pack4(st10));
      pp1 = cat44(pack4(st01), pack4(st11));
    }

    // O^T += V^T . P^T  (key permutation baked into Vws storage order)
    ot[0][0] = mfma32(vf0, pp0, ot[0][0]);  ot[1][0] = mfma32(vf0, pp1, ot[1][0]);
    ot[0][1] = mfma32(vf1, pp0, ot[0][1]);  ot[1][1] = mfma32(vf1, pp1, ot[1][1]);
    ot[0][2] = mfma32(vf2, pp0, ot[0][2]);  ot[1][2] = mfma32(vf2, pp1, ot[1][2]);
    ot[0][3] = mfma32(vf3, pp0, ot[0][3]);  ot[1][3] = mfma32(vf3, pp1, ot[1][3]);
  }

  // column sums live across the 4 quads
  ls0 += __shfl_xor(ls0, 16); ls0 += __shfl_xor(ls0, 32);
  ls1 += __shfl_xor(ls1, 16); ls1 += __shfl_xor(ls1, 32);
  const float inv0 = 1.0f / ls0, inv1 = 1.0f / ls1;

#pragma unroll
  for (int nn = 0; nn < 2; ++nn) {
    const float inv = nn ? inv1 : inv0;
#pragma unroll
    for (int cht = 0; cht < 4; ++cht) {
      float4 v;
      v.x = ot[nn][cht][0] * inv; v.y = ot[nn][cht][1] * inv;
      v.z = ot[nn][cht][2] * inv; v.w = ot[nn][cht][3] * inv;
      *(float4*)(outb + (size_t)(q0 + nn * 16 + l15) * CH + cht * 16 + quad * 4) = v;
    }
  }
}

extern "C" void kernel_launch(void* const* d_in, const int* in_sizes, int n_in,
                              void* d_out, int out_size, void* d_ws, size_t ws_size,
                              hipStream_t stream) {
  const float* x  = (const float*)d_in[0];
  const float* wk = (const float*)d_in[1];   // w_key
  const float* wq = (const float*)d_in[2];   // w_query
  const float* wv = (const float*)d_in[3];   // w_value
  (void)in_sizes; (void)n_in; (void)out_size; (void)ws_size;

  const size_t mat = (size_t)256 * SEQ * CH;           // elements per bf16 matrix
  unsigned short* Qw = (unsigned short*)d_ws;          // 3*mat*2 = 50.3 MB
  unsigned short* Kw = Qw + mat;
  unsigned short* Vw = Kw + mat;

  proj_qkv<<<1024, 256, 0, stream>>>(x, wk, wq, wv, Qw, Kw, Vw);
  attn<<<1024, 256, 0, stream>>>(Qw, Kw, Vw, (float*)d_out);
}

// Round 5
// 119.593 us; speedup vs baseline: 1.6769x; 1.0414x over previous
//
#include <hip/hip_runtime.h>

// Round 5: single fused kernel, one block per batch (256 blocks x 1024 thr).
// K and V live in LDS as MFMA fragment images (R4 layouts) -> all hot reads
// are ds_read_b128 at base+lane*16. Q transposed C->B frag once per strip via
// a wave-private LDS scratch slot (overlaid on ldsK BEFORE K is written).
// exp2 with log2(e) folded into Wq; P packed via v_perm truncation.
// MFMA layouts (guide-verified): A[m=l15][k=q*8+j], B[k=q*8+j][n=l15],
// C/D[row=4q+r][col=l15].

#define SEQ 512
#define CH  64

typedef __attribute__((ext_vector_type(8))) short bf16x8;
typedef __attribute__((ext_vector_type(4))) short bf16x4;
typedef __attribute__((ext_vector_type(4))) float f32x4;

static __device__ __forceinline__ short f2bf(float f) {
  union { float f; unsigned u; } v; v.f = f;
  unsigned r = v.u + 0x7FFFu + ((v.u >> 16) & 1u);   // RNE
  return (short)(r >> 16);
}

static __device__ __forceinline__ bf16x4 pack4(f32x4 v) {
  bf16x4 r;
  r[0] = f2bf(v[0]); r[1] = f2bf(v[1]); r[2] = f2bf(v[2]); r[3] = f2bf(v[3]);
  return r;
}

static __device__ __forceinline__ f32x4 mfma32(bf16x8 a, bf16x8 b, f32x4 c) {
  return __builtin_amdgcn_mfma_f32_16x16x32_bf16(a, b, c, 0, 0, 0);
}

// pack two f32 -> bf16x2 dword by truncation (1 VALU): dst = [hi.b3 hi.b2 lo.b3 lo.b2]
static __device__ __forceinline__ unsigned pperm(float hi, float lo) {
#if defined(__has_builtin) && __has_builtin(__builtin_amdgcn_perm)
  return __builtin_amdgcn_perm(__builtin_bit_cast(unsigned, hi),
                               __builtin_bit_cast(unsigned, lo), 0x07060302u);
#else
  return (__builtin_bit_cast(unsigned, hi) & 0xFFFF0000u) |
         (__builtin_bit_cast(unsigned, lo) >> 16);
#endif
}

#if defined(__has_builtin) && __has_builtin(__builtin_amdgcn_exp2f)
#define EXP2(v) __builtin_amdgcn_exp2f(v)
#else
#define EXP2(v) __expf((v) * 0.6931471805599453f)
#endif

static __device__ __forceinline__ void wave_lds_fence() {
  asm volatile("s_waitcnt lgkmcnt(0)" ::: "memory");
}

__global__ __launch_bounds__(1024, 4)
void attn_fused(const float* __restrict__ x,
                const float* __restrict__ wk,
                const float* __restrict__ wq,
                const float* __restrict__ wv,
                float* __restrict__ out) {
  // frag images: ldsK[i*1024 + c*512 + lane*8 + j] = K[16i+l15][32c+8q+j]
  //              ldsV[g*2048 + nt*512 + lane*8 + j] = V[32g+perm(q,j)][16nt+l15]
  __shared__ alignas(16) unsigned short ldsK[SEQ * CH];   // 64 KB
  __shared__ alignas(16) unsigned short ldsV[SEQ * CH];   // 64 KB

  const int b    = blockIdx.x;
  const int w    = threadIdx.x >> 6;   // wave 0..15
  const int lane = threadIdx.x & 63;
  const int l15  = lane & 15;
  const int quad = lane >> 4;

  // strip assignment: SIMD k (waves w&3==k) gets strips {k,7-k,8+k,15-k}
  // -> every SIMD sums to 34 key-group iterations (balanced tail).
  const int k4 = w & 3, jj = w >> 2;
  const int s  = (jj == 0) ? k4 : (jj == 1) ? 7 - k4 : (jj == 2) ? 8 + k4 : 15 - k4;
  const int q0 = s * 32;

  const float* xb   = x + (size_t)b * SEQ * CH;
  float*       outb = out + (size_t)b * SEQ * CH;

  // ---- Phase A: Q B-frags for own strip, via wave-private scratch in ldsK ----
  bf16x8 qf[2][2];
  {
    bf16x8 WQ[4][2];
#pragma unroll
    for (int t = 0; t < 4; ++t)
#pragma unroll
      for (int c = 0; c < 2; ++c) {
        const int k0 = c * 32 + quad * 8;
        const int n  = t * 16 + l15;
        bf16x8 f;
#pragma unroll
        for (int j = 0; j < 8; ++j)   // fold C^-0.5 * log2(e) -> exp2 later
          f[j] = f2bf(wq[(k0 + j) * CH + n] * 0.18033688011112042f);
        WQ[t][c] = f;
      }
    unsigned short* slot = ldsK + w * 2048;   // 4 KB wave-private scratch
#pragma unroll
    for (int nn = 0; nn < 2; ++nn) {
      bf16x8 xa[2];
#pragma unroll
      for (int c = 0; c < 2; ++c) {
        const float* px = xb + (size_t)(q0 + nn * 16 + l15) * CH + c * 32 + quad * 8;
        float4 lo = *(const float4*)px;
        float4 hi = *(const float4*)(px + 4);
        bf16x8 f;
        f[0] = f2bf(lo.x); f[1] = f2bf(lo.y); f[2] = f2bf(lo.z); f[3] = f2bf(lo.w);
        f[4] = f2bf(hi.x); f[5] = f2bf(hi.y); f[6] = f2bf(hi.z); f[7] = f2bf(hi.w);
        xa[c] = f;
      }
#pragma unroll
      for (int cht = 0; cht < 4; ++cht) {
        f32x4 qt = {0.f, 0.f, 0.f, 0.f};
#pragma unroll
        for (int c = 0; c < 2; ++c)
          qt = mfma32(WQ[cht][c], xa[c], qt);   // Q^T[16cht+4q+r][tok 16nn+l15]
        *(bf16x4*)(slot + (nn * 16 + l15) * 64 + cht * 16 + quad * 4) = pack4(qt);
      }
    }
    wave_lds_fence();   // wave-local write->read, same slot
#pragma unroll
    for (int nn = 0; nn < 2; ++nn)
#pragma unroll
      for (int c = 0; c < 2; ++c)
        qf[nn][c] = *(const bf16x8*)(slot + (nn * 16 + l15) * 64 + c * 32 + quad * 8);
  }
  __syncthreads();   // all waves done with scratch before K image overwrites it

  // ---- Phase B: K,V frag images into LDS; wave w projects tokens [32w,32w+32) ----
  {
    bf16x8 WK[4][2], WV[4][2];
#pragma unroll
    for (int t = 0; t < 4; ++t)
#pragma unroll
      for (int c = 0; c < 2; ++c) {
        const int k0 = c * 32 + quad * 8;
        const int n  = t * 16 + l15;
        bf16x8 fk, fv;
#pragma unroll
        for (int j = 0; j < 8; ++j) {
          fk[j] = f2bf(wk[(k0 + j) * CH + n]);
          fv[j] = f2bf(wv[(k0 + j) * CH + n]);
        }
        WK[t][c] = fk; WV[t][c] = fv;
      }
#pragma unroll
    for (int sub = 0; sub < 2; ++sub) {
      const int t16 = w * 32 + sub * 16;
      bf16x8 xa[2];
#pragma unroll
      for (int c = 0; c < 2; ++c) {
        const float* px = xb + (size_t)(t16 + l15) * CH + c * 32 + quad * 8;
        float4 lo = *(const float4*)px;
        float4 hi = *(const float4*)(px + 4);
        bf16x8 f;
        f[0] = f2bf(lo.x); f[1] = f2bf(lo.y); f[2] = f2bf(lo.z); f[3] = f2bf(lo.w);
        f[4] = f2bf(hi.x); f[5] = f2bf(hi.y); f[6] = f2bf(hi.z); f[7] = f2bf(hi.w);
        xa[c] = f;
      }
#pragma unroll
      for (int cht = 0; cht < 4; ++cht) {   // K^T C-frags -> frag-image store
        f32x4 ak = {0.f, 0.f, 0.f, 0.f};
#pragma unroll
        for (int c = 0; c < 2; ++c)
          ak = mfma32(WK[cht][c], xa[c], ak);
        const int cdst = cht >> 1;
        const int qp   = ((cht & 1) << 1) | (quad >> 1);
        *(bf16x4*)(ldsK + (t16 >> 4) * 1024 + cdst * 512 +
                   (qp * 16 + l15) * 8 + (quad & 1) * 4) = pack4(ak);
      }
#pragma unroll
      for (int nt = 0; nt < 4; ++nt) {      // V C-frags -> key-permuted V^T image
        f32x4 av = {0.f, 0.f, 0.f, 0.f};
#pragma unroll
        for (int c = 0; c < 2; ++c)
          av = mfma32(xa[c], WV[nt][c], av);
        *(bf16x4*)(ldsV + w * 2048 + nt * 512 +
                   (quad * 16 + l15) * 8 + sub * 4) = pack4(av);
      }
    }
  }
  __syncthreads();

  // ---- Phase C: key loop (strip s, 32 q-cols, groups 0..s) ----
  f32x4 ot[2][4];
#pragma unroll
  for (int nn = 0; nn < 2; ++nn)
#pragma unroll
    for (int cht = 0; cht < 4; ++cht) ot[nn][cht] = (f32x4){0.f, 0.f, 0.f, 0.f};
  float ls0 = 0.f, ls1 = 0.f;
  const int dthr = l15 - quad * 4;

#pragma unroll 1
  for (int kt = 0; kt <= s; ++kt) {
    const bool diag = (kt == s);
    const unsigned short* kp = ldsK + kt * 2048;
    const unsigned short* vp = ldsV + kt * 2048;
    bf16x8 kf00 = *(const bf16x8*)(kp + lane * 8);
    bf16x8 kf01 = *(const bf16x8*)(kp + 512 + lane * 8);
    bf16x8 kf10 = *(const bf16x8*)(kp + 1024 + lane * 8);
    bf16x8 kf11 = *(const bf16x8*)(kp + 1536 + lane * 8);
    bf16x8 vf0 = *(const bf16x8*)(vp + lane * 8);
    bf16x8 vf1 = *(const bf16x8*)(vp + 512 + lane * 8);
    bf16x8 vf2 = *(const bf16x8*)(vp + 1024 + lane * 8);
    bf16x8 vf3 = *(const bf16x8*)(vp + 1536 + lane * 8);

    f32x4 st00 = {0.f,0.f,0.f,0.f}, st01 = {0.f,0.f,0.f,0.f};
    f32x4 st10 = {0.f,0.f,0.f,0.f}, st11 = {0.f,0.f,0.f,0.f};
    st00 = mfma32(kf00, qf[0][0], st00); st00 = mfma32(kf01, qf[0][1], st00);
    st01 = mfma32(kf00, qf[1][0], st01); st01 = mfma32(kf01, qf[1][1], st01);
    st11 = mfma32(kf10, qf[1][0], st11); st11 = mfma32(kf11, qf[1][1], st11);
    if (!diag) {
      st10 = mfma32(kf10, qf[0][0], st10); st10 = mfma32(kf11, qf[0][1], st10);
    }

    union { bf16x8 v; unsigned u[4]; } P0, P1;
    if (diag) {
#pragma unroll
      for (int r = 0; r < 4; ++r) {
        st00[r] = (r > dthr) ? 0.f : EXP2(st00[r]);  ls0 += st00[r];
        st11[r] = (r > dthr) ? 0.f : EXP2(st11[r]);  ls1 += st11[r];
        st01[r] = EXP2(st01[r]);                     ls1 += st01[r];
      }
      P0.u[0] = pperm(st00[1], st00[0]); P0.u[1] = pperm(st00[3], st00[2]);
      P0.u[2] = 0u;                      P0.u[3] = 0u;   // keys 16-31 masked for cols 0-15
      P1.u[0] = pperm(st01[1], st01[0]); P1.u[1] = pperm(st01[3], st01[2]);
      P1.u[2] = pperm(st11[1], st11[0]); P1.u[3] = pperm(st11[3], st11[2]);
    } else {
#pragma unroll
      for (int r = 0; r < 4; ++r) {
        st00[r] = EXP2(st00[r]);  ls0 += st00[r];
        st10[r] = EXP2(st10[r]);  ls0 += st10[r];
        st01[r] = EXP2(st01[r]);  ls1 += st01[r];
        st11[r] = EXP2(st11[r]);  ls1 += st11[r];
      }
      P0.u[0] = pperm(st00[1], st00[0]); P0.u[1] = pperm(st00[3], st00[2]);
      P0.u[2] = pperm(st10[1], st10[0]); P0.u[3] = pperm(st10[3], st10[2]);
      P1.u[0] = pperm(st01[1], st01[0]); P1.u[1] = pperm(st01[3], st01[2]);
      P1.u[2] = pperm(st11[1], st11[0]); P1.u[3] = pperm(st11[3], st11[2]);
    }

    ot[0][0] = mfma32(vf0, P0.v, ot[0][0]);  ot[1][0] = mfma32(vf0, P1.v, ot[1][0]);
    ot[0][1] = mfma32(vf1, P0.v, ot[0][1]);  ot[1][1] = mfma32(vf1, P1.v, ot[1][1]);
    ot[0][2] = mfma32(vf2, P0.v, ot[0][2]);  ot[1][2] = mfma32(vf2, P1.v, ot[1][2]);
    ot[0][3] = mfma32(vf3, P0.v, ot[0][3]);  ot[1][3] = mfma32(vf3, P1.v, ot[1][3]);
  }

  // column sums live across the 4 quads
  ls0 += __shfl_xor(ls0, 16); ls0 += __shfl_xor(ls0, 32);
  ls1 += __shfl_xor(ls1, 16); ls1 += __shfl_xor(ls1, 32);
  const float inv0 = 1.0f / ls0, inv1 = 1.0f / ls1;

#pragma unroll
  for (int nn = 0; nn < 2; ++nn) {
    const float inv = nn ? inv1 : inv0;
#pragma unroll
    for (int cht = 0; cht < 4; ++cht) {
      float4 v;
      v.x = ot[nn][cht][0] * inv; v.y = ot[nn][cht][1] * inv;
      v.z = ot[nn][cht][2] * inv; v.w = ot[nn][cht][3] * inv;
      *(float4*)(outb + (size_t)(q0 + nn * 16 + l15) * CH + cht * 16 + quad * 4) = v;
    }
  }
}

extern "C" void kernel_launch(void* const* d_in, const int* in_sizes, int n_in,
                              void* d_out, int out_size, void* d_ws, size_t ws_size,
                              hipStream_t stream) {
  const float* x  = (const float*)d_in[0];
  const float* wk = (const float*)d_in[1];   // w_key
  const float* wq = (const float*)d_in[2];   // w_query
  const float* wv = (const float*)d_in[3];   // w_value
  (void)in_sizes; (void)n_in; (void)out_size; (void)d_ws; (void)ws_size;
  attn_fused<<<256, 1024, 0, stream>>>(x, wk, wq, wv, (float*)d_out);
}

// Round 6
// 100.209 us; speedup vs baseline: 2.0013x; 1.1934x over previous
//
#include <hip/hip_runtime.h>

// Round 6: fused kernel, 256 blocks x 512 threads (8 waves, 2/SIMD).
// Rationale: R5's 1024-thr block forced a 128-reg arch ceiling -> spills
// (WRITE_SIZE +19MB) and a serialized K-loop. 512 threads => 256-reg budget:
// zero spill + explicit kf prefetch + vf loads hoisted ahead of the exp chain.
// Wave w owns strips {w, 15-w} = exactly 17 key-tile iterations each.
// Weights converted to MFMA frag images ONCE per block (cooperative, LDS).
// K/V LDS frag images (R4/R5 layouts): all hot reads ds_read_b128 base+lane*16.
// MFMA layouts (guide-verified): A[m=l15][k=q*8+j], B[k=q*8+j][n=l15],
// C/D[row=4q+r][col=l15].

#define SEQ 512
#define CH  64

#define SLOT_STRIDE 72                    // padded Q-transpose slot row (shorts)
#define SLOT_SIZE   (32 * SLOT_STRIDE)    // 2304 shorts per wave
#define WOFF        (8 * SLOT_SIZE)       // weight frag images at ldsK + 18432

typedef __attribute__((ext_vector_type(8))) short bf16x8;
typedef __attribute__((ext_vector_type(4))) short bf16x4;
typedef __attribute__((ext_vector_type(4))) float f32x4;

static __device__ __forceinline__ short f2bf(float f) {
  union { float f; unsigned u; } v; v.f = f;
  unsigned r = v.u + 0x7FFFu + ((v.u >> 16) & 1u);   // RNE
  return (short)(r >> 16);
}

static __device__ __forceinline__ bf16x4 pack4(f32x4 v) {
  bf16x4 r;
  r[0] = f2bf(v[0]); r[1] = f2bf(v[1]); r[2] = f2bf(v[2]); r[3] = f2bf(v[3]);
  return r;
}

static __device__ __forceinline__ f32x4 mfma32(bf16x8 a, bf16x8 b, f32x4 c) {
  return __builtin_amdgcn_mfma_f32_16x16x32_bf16(a, b, c, 0, 0, 0);
}

// pack two f32 -> bf16x2 dword by truncation (1 VALU)
static __device__ __forceinline__ unsigned pperm(float hi, float lo) {
#if defined(__has_builtin) && __has_builtin(__builtin_amdgcn_perm)
  return __builtin_amdgcn_perm(__builtin_bit_cast(unsigned, hi),
                               __builtin_bit_cast(unsigned, lo), 0x07060302u);
#else
  return (__builtin_bit_cast(unsigned, hi) & 0xFFFF0000u) |
         (__builtin_bit_cast(unsigned, lo) >> 16);
#endif
}

#if defined(__has_builtin) && __has_builtin(__builtin_amdgcn_exp2f)
#define EXP2(v) __builtin_amdgcn_exp2f(v)
#else
#define EXP2(v) __expf((v) * 0.6931471805599453f)
#endif

static __device__ __forceinline__ void wave_lds_fence() {
  asm volatile("s_waitcnt lgkmcnt(0)" ::: "memory");
}

// Q fragments for one 32-row strip via the wave-private padded slot.
static __device__ __forceinline__ void make_qf(
    const float* __restrict__ xb, const bf16x8 WQf[4][2],
    unsigned short* slot, int q0, int l15, int quad, bf16x8 qf[2][2]) {
#pragma unroll
  for (int nn = 0; nn < 2; ++nn) {
    bf16x8 xa[2];
#pragma unroll
    for (int c = 0; c < 2; ++c) {
      const float* px = xb + (size_t)(q0 + nn * 16 + l15) * CH + c * 32 + quad * 8;
      float4 lo = *(const float4*)px;
      float4 hi = *(const float4*)(px + 4);
      bf16x8 f;
      f[0] = f2bf(lo.x); f[1] = f2bf(lo.y); f[2] = f2bf(lo.z); f[3] = f2bf(lo.w);
      f[4] = f2bf(hi.x); f[5] = f2bf(hi.y); f[6] = f2bf(hi.z); f[7] = f2bf(hi.w);
      xa[c] = f;
    }
#pragma unroll
    for (int cht = 0; cht < 4; ++cht) {
      f32x4 qt = {0.f, 0.f, 0.f, 0.f};
#pragma unroll
      for (int c = 0; c < 2; ++c)
        qt = mfma32(WQf[cht][c], xa[c], qt);   // Q^T[16cht+4q+r][q0+16nn+l15]
      *(bf16x4*)(slot + (nn * 16 + l15) * SLOT_STRIDE + cht * 16 + quad * 4) = pack4(qt);
    }
  }
  wave_lds_fence();
#pragma unroll
  for (int nn = 0; nn < 2; ++nn)
#pragma unroll
    for (int c = 0; c < 2; ++c)
      qf[nn][c] = *(const bf16x8*)(slot + (nn * 16 + l15) * SLOT_STRIDE + c * 32 + quad * 8);
  wave_lds_fence();   // drain reads before slot is overwritten
}

// One 32-query strip: prefetched key loop + epilogue.
static __device__ __forceinline__ void run_strip(
    int s, const bf16x8 qf[2][2], const unsigned short* __restrict__ ldsK,
    const unsigned short* __restrict__ ldsV, float* __restrict__ outb,
    int lane, int l15, int quad) {
  const int q0 = s * 32;
  f32x4 ot[2][4];
#pragma unroll
  for (int nn = 0; nn < 2; ++nn)
#pragma unroll
    for (int cht = 0; cht < 4; ++cht) ot[nn][cht] = (f32x4){0.f, 0.f, 0.f, 0.f};
  float ls0 = 0.f, ls1 = 0.f;
  const int dthr = l15 - quad * 4;

  bf16x8 kf[4];
#pragma unroll
  for (int i = 0; i < 4; ++i)
    kf[i] = *(const bf16x8*)(ldsK + i * 512 + lane * 8);   // kt = 0

#pragma unroll 1
  for (int kt = 0; kt <= s; ++kt) {
    const bool diag = (kt == s);
    // vf issued early: consumed only after the exp chain
    bf16x8 vf[4];
    const unsigned short* vp = ldsV + kt * 2048;
#pragma unroll
    for (int i = 0; i < 4; ++i)
      vf[i] = *(const bf16x8*)(vp + i * 512 + lane * 8);
    // prefetch next K tile
    bf16x8 kn[4];
    if (!diag) {
      const unsigned short* kp = ldsK + (kt + 1) * 2048;
#pragma unroll
      for (int i = 0; i < 4; ++i)
        kn[i] = *(const bf16x8*)(kp + i * 512 + lane * 8);
    }

    // S^T subtiles: st[mm][nn], rows=keys 32kt+16mm+4q+r, cols=q0+16nn+l15
    f32x4 st00 = {0.f,0.f,0.f,0.f}, st01 = {0.f,0.f,0.f,0.f};
    f32x4 st10 = {0.f,0.f,0.f,0.f}, st11 = {0.f,0.f,0.f,0.f};
    st00 = mfma32(kf[0], qf[0][0], st00); st00 = mfma32(kf[1], qf[0][1], st00);
    st01 = mfma32(kf[0], qf[1][0], st01); st01 = mfma32(kf[1], qf[1][1], st01);
    st11 = mfma32(kf[2], qf[1][0], st11); st11 = mfma32(kf[3], qf[1][1], st11);
    if (!diag) {
      st10 = mfma32(kf[2], qf[0][0], st10); st10 = mfma32(kf[3], qf[0][1], st10);
    }

    union { bf16x8 v; unsigned u[4]; } P0, P1;
    if (diag) {
#pragma unroll
      for (int r = 0; r < 4; ++r) {
        st00[r] = (r > dthr) ? 0.f : EXP2(st00[r]);  ls0 += st00[r];
        st11[r] = (r > dthr) ? 0.f : EXP2(st11[r]);  ls1 += st11[r];
        st01[r] = EXP2(st01[r]);                     ls1 += st01[r];
      }
      P0.u[0] = pperm(st00[1], st00[0]); P0.u[1] = pperm(st00[3], st00[2]);
      P0.u[2] = 0u;                      P0.u[3] = 0u;   // keys 16-31 masked for cols 0-15
      P1.u[0] = pperm(st01[1], st01[0]); P1.u[1] = pperm(st01[3], st01[2]);
      P1.u[2] = pperm(st11[1], st11[0]); P1.u[3] = pperm(st11[3], st11[2]);
    } else {
#pragma unroll
      for (int r = 0; r < 4; ++r) {
        st00[r] = EXP2(st00[r]);  ls0 += st00[r];
        st10[r] = EXP2(st10[r]);  ls0 += st10[r];
        st01[r] = EXP2(st01[r]);  ls1 += st01[r];
        st11[r] = EXP2(st11[r]);  ls1 += st11[r];
      }
      P0.u[0] = pperm(st00[1], st00[0]); P0.u[1] = pperm(st00[3], st00[2]);
      P0.u[2] = pperm(st10[1], st10[0]); P0.u[3] = pperm(st10[3], st10[2]);
      P1.u[0] = pperm(st01[1], st01[0]); P1.u[1] = pperm(st01[3], st01[2]);
      P1.u[2] = pperm(st11[1], st11[0]); P1.u[3] = pperm(st11[3], st11[2]);
    }

    // O^T += V^T . P^T  (key permutation baked into V image order)
    ot[0][0] = mfma32(vf[0], P0.v, ot[0][0]);  ot[1][0] = mfma32(vf[0], P1.v, ot[1][0]);
    ot[0][1] = mfma32(vf[1], P0.v, ot[0][1]);  ot[1][1] = mfma32(vf[1], P1.v, ot[1][1]);
    ot[0][2] = mfma32(vf[2], P0.v, ot[0][2]);  ot[1][2] = mfma32(vf[2], P1.v, ot[1][2]);
    ot[0][3] = mfma32(vf[3], P0.v, ot[0][3]);  ot[1][3] = mfma32(vf[3], P1.v, ot[1][3]);

    if (!diag) {
#pragma unroll
      for (int i = 0; i < 4; ++i) kf[i] = kn[i];
    }
  }

  // column sums live across the 4 quads
  ls0 += __shfl_xor(ls0, 16); ls0 += __shfl_xor(ls0, 32);
  ls1 += __shfl_xor(ls1, 16); ls1 += __shfl_xor(ls1, 32);
  const float inv0 = 1.0f / ls0, inv1 = 1.0f / ls1;

#pragma unroll
  for (int nn = 0; nn < 2; ++nn) {
    const float inv = nn ? inv1 : inv0;
#pragma unroll
    for (int cht = 0; cht < 4; ++cht) {
      float4 v;
      v.x = ot[nn][cht][0] * inv; v.y = ot[nn][cht][1] * inv;
      v.z = ot[nn][cht][2] * inv; v.w = ot[nn][cht][3] * inv;
      *(float4*)(outb + (size_t)(q0 + nn * 16 + l15) * CH + cht * 16 + quad * 4) = v;
    }
  }
}

__global__ __launch_bounds__(512, 2)
void attn_fused(const float* __restrict__ x,
                const float* __restrict__ wk,
                const float* __restrict__ wq,
                const float* __restrict__ wv,
                float* __restrict__ out) {
  // ldsK: finally the K frag image (64 KB); before that, overlaid:
  //   [0, 18432)        8 wave-private padded Q-transpose slots (36 KB)
  //   [18432, 30720)    24 weight frag images, 512 shorts each (24 KB)
  // ldsV: V frag image (64 KB), written in phase B only.
  __shared__ alignas(16) unsigned short ldsK[SEQ * CH];
  __shared__ alignas(16) unsigned short ldsV[SEQ * CH];

  const int b    = blockIdx.x;
  const int w    = threadIdx.x >> 6;   // wave 0..7
  const int lane = threadIdx.x & 63;
  const int l15  = lane & 15;
  const int quad = lane >> 4;

  const float* xb   = x + (size_t)b * SEQ * CH;
  float*       outb = out + (size_t)b * SEQ * CH;

  // ---- P0: cooperative weight frag-image build (wave w -> chunk w of each matrix)
  {
    const int t = w >> 1, c = w & 1;
    const int k0 = c * 32 + quad * 8;
    const int n  = t * 16 + l15;
#pragma unroll
    for (int m = 0; m < 3; ++m) {
      const float* Wsrc  = (m == 0) ? wq : (m == 1) ? wk : wv;
      const float  scale = (m == 0) ? 0.18033688011112042f : 1.0f;  // C^-0.5*log2e
      bf16x8 fr;
#pragma unroll
      for (int j = 0; j < 8; ++j)
        fr[j] = f2bf(Wsrc[(k0 + j) * CH + n] * scale);
      *(bf16x8*)(ldsK + WOFF + (m * 8 + w) * 512 + lane * 8) = fr;
    }
  }
  __syncthreads();

  // ---- PA: Q fragments for strips {w, 15-w}
  const int sA = w, sB = 15 - w;
  unsigned short* slot = ldsK + w * SLOT_SIZE;
  bf16x8 qfA[2][2], qfB[2][2];
  {
    bf16x8 WQf[4][2];
#pragma unroll
    for (int t = 0; t < 4; ++t)
#pragma unroll
      for (int c = 0; c < 2; ++c)
        WQf[t][c] = *(const bf16x8*)(ldsK + WOFF + (t * 2 + c) * 512 + lane * 8);
    make_qf(xb, WQf, slot, sA * 32, l15, quad, qfA);
    make_qf(xb, WQf, slot, sB * 32, l15, quad, qfB);
  }

  // ---- PB: K,V frag images; wave w projects tokens [64w, 64w+64)
  {
    bf16x8 WKf[4][2], WVf[4][2];
#pragma unroll
    for (int t = 0; t < 4; ++t)
#pragma unroll
      for (int c = 0; c < 2; ++c) {
        WKf[t][c] = *(const bf16x8*)(ldsK + WOFF + (8  + t * 2 + c) * 512 + lane * 8);
        WVf[t][c] = *(const bf16x8*)(ldsK + WOFF + (16 + t * 2 + c) * 512 + lane * 8);
      }
    __syncthreads();   // slots + weight area free before K image overwrites them

#pragma unroll
    for (int sub = 0; sub < 4; ++sub) {
      const int t16 = w * 64 + sub * 16;
      bf16x8 xa[2];
#pragma unroll
      for (int c = 0; c < 2; ++c) {
        const float* px = xb + (size_t)(t16 + l15) * CH + c * 32 + quad * 8;
        float4 lo = *(const float4*)px;
        float4 hi = *(const float4*)(px + 4);
        bf16x8 f;
        f[0] = f2bf(lo.x); f[1] = f2bf(lo.y); f[2] = f2bf(lo.z); f[3] = f2bf(lo.w);
        f[4] = f2bf(hi.x); f[5] = f2bf(hi.y); f[6] = f2bf(hi.z); f[7] = f2bf(hi.w);
        xa[c] = f;
      }
#pragma unroll
      for (int cht = 0; cht < 4; ++cht) {   // K^T C-frags -> frag-image store
        f32x4 ak = {0.f, 0.f, 0.f, 0.f};
#pragma unroll
        for (int c = 0; c < 2; ++c)
          ak = mfma32(WKf[cht][c], xa[c], ak);
        const int cdst = cht >> 1;
        const int qp   = ((cht & 1) << 1) | (quad >> 1);
        *(bf16x4*)(ldsK + (t16 >> 4) * 1024 + cdst * 512 +
                   (qp * 16 + l15) * 8 + (quad & 1) * 4) = pack4(ak);
      }
#pragma unroll
      for (int nt = 0; nt < 4; ++nt) {      // V C-frags -> key-permuted V^T image
        f32x4 av = {0.f, 0.f, 0.f, 0.f};
#pragma unroll
        for (int c = 0; c < 2; ++c)
          av = mfma32(xa[c], WVf[nt][c], av);
        *(bf16x4*)(ldsV + (t16 >> 5) * 2048 + nt * 512 +
                   (quad * 16 + l15) * 8 + ((t16 >> 4) & 1) * 4) = pack4(av);
      }
    }
  }
  __syncthreads();

  // ---- PC: two balanced strips (w+1) + (16-w) = 17 key-tiles per wave
  run_strip(sA, qfA, ldsK, ldsV, outb, lane, l15, quad);
  run_strip(sB, qfB, ldsK, ldsV, outb, lane, l15, quad);
}

extern "C" void kernel_launch(void* const* d_in, const int* in_sizes, int n_in,
                              void* d_out, int out_size, void* d_ws, size_t ws_size,
                              hipStream_t stream) {
  const float* x  = (const float*)d_in[0];
  const float* wk = (const float*)d_in[1];   // w_key
  const float* wq = (const float*)d_in[2];   // w_query
  const float* wv = (const float*)d_in[3];   // w_value
  (void)in_sizes; (void)n_in; (void)out_size; (void)d_ws; (void)ws_size;
  attn_fused<<<256, 512, 0, stream>>>(x, wk, wq, wv, (float*)d_out);
}